// Round 1
// baseline (308.050 us; speedup 1.0000x reference)
//
#include <hip/hip_runtime.h>
#include <hip/hip_bf16.h>

// HeteroGNN: 2-relation 2-layer GAT + pairwise linear head.
// Key simplification: out[i*N+j] = q[i] + q[j] + b_lin with q = (h2+bias)@w_lin.

#define NEG_SLOPE 0.2f

static __device__ __forceinline__ float lrelu(float x){ return x > 0.f ? x : NEG_SLOPE * x; }

// ---------------- CSR build (by dst), shared across both layers ----------------
__global__ void hist_kernel(const int* __restrict__ ei, int E, int Nn, int* __restrict__ cnt){
    int e = blockIdx.x * blockDim.x + threadIdx.x;
    int tot = E + Nn;
    if (e < tot){
        int dst = (e < E) ? ei[E + e] : (e - E);   // self-loops appended
        atomicAdd(&cnt[dst], 1);
    }
}

__global__ __launch_bounds__(1024) void scan_kernel(const int* __restrict__ cnt,
                                                    int* __restrict__ row_ptr,
                                                    int* __restrict__ fill){
    __shared__ int s[1024];
    int tid = threadIdx.x;
    int c = cnt[tid];
    s[tid] = c;
    __syncthreads();
    for (int off = 1; off < 1024; off <<= 1){
        int v = (tid >= off) ? s[tid - off] : 0;
        __syncthreads();
        s[tid] += v;
        __syncthreads();
    }
    row_ptr[tid + 1] = s[tid];        // inclusive -> row_ptr[1..1024]
    if (tid == 0) row_ptr[0] = 0;
    fill[tid] = s[tid] - c;           // exclusive, used as scatter cursor
}

__global__ void scatter_kernel(const int* __restrict__ ei, int E, int Nn,
                               int* __restrict__ fill, int* __restrict__ csr_src){
    int e = blockIdx.x * blockDim.x + threadIdx.x;
    int tot = E + Nn;
    if (e < tot){
        int src, dst;
        if (e < E){ src = ei[e]; dst = ei[E + e]; } else { src = dst = e - E; }
        int pos = atomicAdd(&fill[dst], 1);
        csr_src[pos] = src;
    }
}

// ---------------- fp32 tiled GEMM: C_r = A @ B_r for both relations ----------------
template<int BM, int BN, int BK, int TM, int TN>
__global__ __launch_bounds__((BM/TM)*(BN/TN))
void gemm_f32(const float* __restrict__ A,
              const float* __restrict__ B0, const float* __restrict__ B1,
              float* __restrict__ C0, float* __restrict__ C1,
              int M, int Nn, int K){
    constexpr int NT = (BM/TM) * (BN/TN);
    const float* Bm = blockIdx.z ? B1 : B0;
    float*       C  = blockIdx.z ? C1 : C0;
    int m0 = blockIdx.y * BM, n0 = blockIdx.x * BN;
    __shared__ float As[BK][BM + 4];
    __shared__ float Bs[BK][BN + 4];
    int tid = threadIdx.x;
    int tx = tid % (BN/TN), ty = tid / (BN/TN);
    float acc[TM][TN] = {};
    for (int k0 = 0; k0 < K; k0 += BK){
        for (int idx = tid; idx < BM*BK; idx += NT){
            int m = idx / BK, kk = idx % BK;
            As[kk][m] = A[(size_t)(m0 + m) * K + k0 + kk];
        }
        for (int idx = tid; idx < BK*BN; idx += NT){
            int kk = idx / BN, nn = idx % BN;
            Bs[kk][nn] = Bm[(size_t)(k0 + kk) * Nn + n0 + nn];
        }
        __syncthreads();
        #pragma unroll
        for (int kk = 0; kk < BK; kk++){
            float ar[TM], br[TN];
            #pragma unroll
            for (int i = 0; i < TM; i++) ar[i] = As[kk][ty*TM + i];
            #pragma unroll
            for (int j = 0; j < TN; j++) br[j] = Bs[kk][tx*TN + j];
            #pragma unroll
            for (int i = 0; i < TM; i++)
                #pragma unroll
                for (int j = 0; j < TN; j++)
                    acc[i][j] += ar[i] * br[j];
        }
        __syncthreads();
    }
    #pragma unroll
    for (int i = 0; i < TM; i++)
        #pragma unroll
        for (int j = 0; j < TN; j++)
            C[(size_t)(m0 + ty*TM + i) * Nn + n0 + tx*TN + j] = acc[i][j];
}

// ---------------- per-node attention logits: al_s[n,h] = sum_c xp[n,h,c]*a_src[h,c] ----------------
template<int C>   // channels per head; block = 2*C threads, one block per node
__global__ __launch_bounds__(2*C)
void attn_logits(const float* __restrict__ xp, const float* __restrict__ asrc,
                 const float* __restrict__ adst,
                 float* __restrict__ als, float* __restrict__ ald){
    constexpr int HC = 2 * C;
    int n = blockIdx.x, tid = threadIdx.x;
    float v  = xp[(size_t)n * HC + tid];
    float ps = v * asrc[tid];
    float pd = v * adst[tid];
    #pragma unroll
    for (int o = 32; o > 0; o >>= 1){
        ps += __shfl_down(ps, o, 64);
        pd += __shfl_down(pd, o, 64);
    }
    __shared__ float rs[HC/64], rd[HC/64];
    int w = tid >> 6;
    if ((tid & 63) == 0){ rs[w] = ps; rd[w] = pd; }
    __syncthreads();
    if (tid == 0){
        constexpr int WPH = C / 64;   // waves per head
        float S0=0, D0=0, S1=0, D1=0;
        #pragma unroll
        for (int i = 0; i < WPH; i++){
            S0 += rs[i];        D0 += rd[i];
            S1 += rs[WPH + i];  D1 += rd[WPH + i];
        }
        als[n*2+0] = S0; ald[n*2+0] = D0;
        als[n*2+1] = S1; ald[n*2+1] = D1;
    }
}

// ---------------- GAT aggregation: out[v,h,c] += sum_e softmax-wt * xp[src_e,h,c] ----------------
// One block per destination node. Softmax skips max-subtraction (exact-math invariant,
// logits are O(+-10)); every segment is non-empty (self-loops).
template<int HC, int C, int BLOCK, int TILE>
__global__ __launch_bounds__(BLOCK)
void gat_agg(const float* __restrict__ xp, const float* __restrict__ als,
             const float* __restrict__ ald, const int* __restrict__ csr_src,
             const int* __restrict__ row_ptr, float* __restrict__ out){
    constexpr int OPT = HC / BLOCK;
    int v = blockIdx.x, tid = threadIdx.x;
    int beg = row_ptr[v], end = row_ptr[v+1];
    float ald0 = ald[v*2+0], ald1 = ald[v*2+1];

    // pass 1: denominators per head
    float s0 = 0.f, s1 = 0.f;
    for (int e = beg + tid; e < end; e += BLOCK){
        int src = csr_src[e];
        s0 += __expf(lrelu(als[src*2+0] + ald0));
        s1 += __expf(lrelu(als[src*2+1] + ald1));
    }
    #pragma unroll
    for (int o = 32; o > 0; o >>= 1){
        s0 += __shfl_down(s0, o, 64);
        s1 += __shfl_down(s1, o, 64);
    }
    __shared__ float r0[BLOCK/64], r1[BLOCK/64];
    __shared__ float inv0s, inv1s;
    int w = tid >> 6;
    if ((tid & 63) == 0){ r0[w] = s0; r1[w] = s1; }
    __syncthreads();
    if (tid == 0){
        float S0 = 0.f, S1 = 0.f;
        #pragma unroll
        for (int i = 0; i < BLOCK/64; i++){ S0 += r0[i]; S1 += r1[i]; }
        inv0s = 1.f / (S0 + 1e-16f);
        inv1s = 1.f / (S1 + 1e-16f);
    }
    __syncthreads();
    float inv0 = inv0s, inv1 = inv1s;

    // pass 2: chunked weighted gather
    __shared__ float wa0[TILE], wa1[TILE];
    __shared__ int   ssrc[TILE];
    float acc[OPT] = {};
    for (int cb = beg; cb < end; cb += TILE){
        int n = min(TILE, end - cb);
        __syncthreads();
        for (int i = tid; i < n; i += BLOCK){
            int src = csr_src[cb + i];
            ssrc[i] = src * HC;
            wa0[i] = __expf(lrelu(als[src*2+0] + ald0)) * inv0;
            wa1[i] = __expf(lrelu(als[src*2+1] + ald1)) * inv1;
        }
        __syncthreads();
        #pragma unroll 4
        for (int i = 0; i < n; i++){
            int sb = ssrc[i];
            float a0 = wa0[i], a1 = wa1[i];
            #pragma unroll
            for (int rp = 0; rp < OPT; rp++){
                int o = tid + rp * BLOCK;
                float a = (o < C) ? a0 : a1;
                acc[rp] += xp[(size_t)sb + o] * a;
            }
        }
    }
    #pragma unroll
    for (int rp = 0; rp < OPT; rp++)
        out[(size_t)v * HC + tid + rp*BLOCK] += acc[rp];
}

// ---------------- h1 = relu(h1 + b1_0 + b1_1) ----------------
template<int HC>
__global__ void bias_relu(float* __restrict__ h, const float* __restrict__ b0,
                          const float* __restrict__ b1, int total){
    int idx = blockIdx.x * blockDim.x + threadIdx.x;
    if (idx < total){
        int c = idx & (HC - 1);
        float t = h[idx] + b0[c] + b1[c];
        h[idx] = t > 0.f ? t : 0.f;
    }
}

// ---------------- q[n] = sum_c (h2[n,c] + b2_0[c] + b2_1[c]) * w_lin[c] ----------------
__global__ __launch_bounds__(128)
void node_q(const float* __restrict__ h2, const float* __restrict__ b0,
            const float* __restrict__ b1, const float* __restrict__ wl,
            float* __restrict__ q){
    int n = blockIdx.x, tid = threadIdx.x;
    float v = (h2[(size_t)n * 128 + tid] + b0[tid] + b1[tid]) * wl[tid];
    #pragma unroll
    for (int o = 32; o > 0; o >>= 1) v += __shfl_down(v, o, 64);
    __shared__ float r[2];
    if ((tid & 63) == 0) r[tid >> 6] = v;
    __syncthreads();
    if (tid == 0) q[n] = r[0] + r[1];
}

// ---------------- out[i*1024 + j] = q[i] + q[j] + b_lin ----------------
__global__ __launch_bounds__(256)
void pairs_out(const float* __restrict__ q, const float* __restrict__ blin,
               float* __restrict__ out){
    int i = blockIdx.x;
    float qi = q[i] + blin[0];
    float4 qj = ((const float4*)q)[threadIdx.x];
    float4 o;
    o.x = qi + qj.x; o.y = qi + qj.y; o.z = qi + qj.z; o.w = qi + qj.w;
    ((float4*)out)[(size_t)i * 256 + threadIdx.x] = o;
}

extern "C" void kernel_launch(void* const* d_in, const int* in_sizes, int n_in,
                              void* d_out, int out_size, void* d_ws, size_t ws_size,
                              hipStream_t stream){
    const float* x    = (const float*)d_in[0];
    const int*   ei[2]  = {(const int*)d_in[1], (const int*)d_in[2]};
    const float* W1[2]  = {(const float*)d_in[3],  (const float*)d_in[7]};
    const float* as1[2] = {(const float*)d_in[4],  (const float*)d_in[8]};
    const float* ad1[2] = {(const float*)d_in[5],  (const float*)d_in[9]};
    const float* b1[2]  = {(const float*)d_in[6],  (const float*)d_in[10]};
    const float* W2[2]  = {(const float*)d_in[11], (const float*)d_in[15]};
    const float* as2[2] = {(const float*)d_in[12], (const float*)d_in[16]};
    const float* ad2[2] = {(const float*)d_in[13], (const float*)d_in[17]};
    const float* b2[2]  = {(const float*)d_in[14], (const float*)d_in[18]};
    const float* wlin = (const float*)d_in[19];
    const float* blin = (const float*)d_in[20];
    float* out = (float*)d_out;

    const int N = 1024;
    const int E = in_sizes[1] / 2;
    const int TOT = E + N;

    // ---- workspace layout (bump allocator, 256B aligned) ----
    char* p = (char*)d_ws;
    auto alloc = [&](size_t bytes) -> char* {
        char* r = p; p += (bytes + 255) & ~(size_t)255; return r;
    };
    float* xp1[2] = {(float*)alloc((size_t)N*512*4), (float*)alloc((size_t)N*512*4)};
    float* h1     = (float*)alloc((size_t)N*512*4);
    float* xp2[2] = {(float*)alloc((size_t)N*128*4), (float*)alloc((size_t)N*128*4)};
    float* h2     = (float*)alloc((size_t)N*128*4);
    float* als1[2] = {(float*)alloc(N*2*4), (float*)alloc(N*2*4)};
    float* ald1[2] = {(float*)alloc(N*2*4), (float*)alloc(N*2*4)};
    float* als2[2] = {(float*)alloc(N*2*4), (float*)alloc(N*2*4)};
    float* ald2[2] = {(float*)alloc(N*2*4), (float*)alloc(N*2*4)};
    int* cnt   = (int*)alloc((size_t)2*N*4);            // cnt[0..N), cnt[N..2N)
    int* rowp[2] = {(int*)alloc((N+1)*4), (int*)alloc((N+1)*4)};
    int* fill[2] = {(int*)alloc(N*4), (int*)alloc(N*4)};
    int* csr[2]  = {(int*)alloc((size_t)TOT*4), (int*)alloc((size_t)TOT*4)};
    float* q   = (float*)alloc(N*4);

    // ---- zero accumulators / counters ----
    hipMemsetAsync(cnt, 0, (size_t)2*N*4, stream);
    hipMemsetAsync(h1, 0, (size_t)N*512*4, stream);
    hipMemsetAsync(h2, 0, (size_t)N*128*4, stream);

    int eb = (TOT + 255) / 256;
    // ---- CSR per relation (shared by both layers) ----
    for (int r = 0; r < 2; r++){
        hist_kernel<<<eb, 256, 0, stream>>>(ei[r], E, N, cnt + r*N);
        scan_kernel<<<1, 1024, 0, stream>>>(cnt + r*N, rowp[r], fill[r]);
        scatter_kernel<<<eb, 256, 0, stream>>>(ei[r], E, N, fill[r], csr[r]);
    }

    // ---- layer 1: xp1_r = x @ W1_r  [1024,256]@[256,512] ----
    gemm_f32<64,64,16,4,4><<<dim3(512/64, 1024/64, 2), 256, 0, stream>>>(
        x, W1[0], W1[1], xp1[0], xp1[1], 1024, 512, 256);
    for (int r = 0; r < 2; r++)
        attn_logits<256><<<N, 512, 0, stream>>>(xp1[r], as1[r], ad1[r], als1[r], ald1[r]);
    for (int r = 0; r < 2; r++)
        gat_agg<512,256,256,1024><<<N, 256, 0, stream>>>(
            xp1[r], als1[r], ald1[r], csr[r], rowp[r], h1);
    bias_relu<512><<<(N*512)/256, 256, 0, stream>>>(h1, b1[0], b1[1], N*512);

    // ---- layer 2: xp2_r = h1 @ W2_r  [1024,512]@[512,128] ----
    gemm_f32<32,32,32,2,2><<<dim3(128/32, 1024/32, 2), 256, 0, stream>>>(
        h1, W2[0], W2[1], xp2[0], xp2[1], 1024, 128, 512);
    for (int r = 0; r < 2; r++)
        attn_logits<64><<<N, 128, 0, stream>>>(xp2[r], as2[r], ad2[r], als2[r], ald2[r]);
    for (int r = 0; r < 2; r++)
        gat_agg<128,64,128,1024><<<N, 128, 0, stream>>>(
            xp2[r], als2[r], ald2[r], csr[r], rowp[r], h2);

    // ---- head: q = (h2 + biases) @ w_lin; out[i,j] = q[i]+q[j]+b ----
    node_q<<<N, 128, 0, stream>>>(h2, b2[0], b2[1], wlin, q);
    pairs_out<<<N, 256, 0, stream>>>(q, blin, out);
}

// Round 2
// 211.339 us; speedup vs baseline: 1.4576x; 1.4576x over previous
//
#include <hip/hip_runtime.h>
#include <hip/hip_bf16.h>

// HeteroGNN: 2-relation 2-layer GAT + pairwise linear head.
// out[i*N+j] = q[i] + q[j] + b_lin with q = (h2 + biases) @ w_lin  (head collapses).
// Logits via associativity: al = (x@W)·a = x @ (W·a)  -> tiny v-matrix, no xp re-read.

#define NEG_SLOPE 0.2f
static __device__ __forceinline__ float lrelu(float x){ return x > 0.f ? x : NEG_SLOPE * x; }

// ---------------- CSR build (by dst), both relations per launch ----------------
__global__ void hist_kernel(const int* __restrict__ ei0, const int* __restrict__ ei1,
                            int E, int Nn, int* __restrict__ cnt){
    const int* ei = blockIdx.y ? ei1 : ei0;
    int* c = cnt + blockIdx.y * Nn;
    int e = blockIdx.x * blockDim.x + threadIdx.x;
    if (e < E + Nn){
        int dst = (e < E) ? ei[E + e] : (e - E);   // self-loops appended
        atomicAdd(&c[dst], 1);
    }
}

__global__ __launch_bounds__(1024)
void scan_kernel(const int* __restrict__ cnt,
                 int* __restrict__ rowp0, int* __restrict__ rowp1,
                 int* __restrict__ fill0, int* __restrict__ fill1){
    int r = blockIdx.x;
    const int* cn = cnt + r * 1024;
    int* rowp = r ? rowp1 : rowp0;
    int* fill = r ? fill1 : fill0;
    __shared__ int s[1024];
    int tid = threadIdx.x;
    int c = cn[tid];
    s[tid] = c; __syncthreads();
    for (int off = 1; off < 1024; off <<= 1){
        int v = (tid >= off) ? s[tid - off] : 0;
        __syncthreads();
        s[tid] += v;
        __syncthreads();
    }
    rowp[tid + 1] = s[tid];
    if (tid == 0) rowp[0] = 0;
    fill[tid] = s[tid] - c;
}

__global__ void scatter_kernel(const int* __restrict__ ei0, const int* __restrict__ ei1,
                               int E, int Nn,
                               int* __restrict__ fill0, int* __restrict__ fill1,
                               int* __restrict__ csr0, int* __restrict__ csr1){
    const int* ei = blockIdx.y ? ei1 : ei0;
    int* fill = blockIdx.y ? fill1 : fill0;
    int* csr  = blockIdx.y ? csr1  : csr0;
    int e = blockIdx.x * blockDim.x + threadIdx.x;
    if (e < E + Nn){
        int src, dst;
        if (e < E){ src = ei[e]; dst = ei[E + e]; } else { src = dst = e - E; }
        csr[atomicAdd(&fill[dst], 1)] = src;
    }
}

// ---------------- v = W·a  precompute (logit weight vectors), j-major ----------------
// v1: [8][256], v2: [8][512]; j = r*4 + {0:src h0, 1:src h1, 2:dst h0, 3:dst h1}
__global__ __launch_bounds__(64)
void prep_v(const float* __restrict__ W1_0, const float* __restrict__ as1_0,
            const float* __restrict__ ad1_0,
            const float* __restrict__ W1_1, const float* __restrict__ as1_1,
            const float* __restrict__ ad1_1,
            const float* __restrict__ W2_0, const float* __restrict__ as2_0,
            const float* __restrict__ ad2_0,
            const float* __restrict__ W2_1, const float* __restrict__ as2_1,
            const float* __restrict__ ad2_1,
            float* __restrict__ v1, float* __restrict__ v2){
    int id = blockIdx.x, lane = threadIdx.x;
    float sum = 0.f;
    if (id < 2048){                      // layer 1: 8 j x 256 k, C=256
        int j = id >> 8, k = id & 255;
        int r = j >> 2, jj = j & 3, h = jj & 1;
        const float* W = r ? W1_1 : W1_0;                 // [256 x 512]
        const float* a = (jj < 2) ? (r ? as1_1 : as1_0) : (r ? ad1_1 : ad1_0);
        const float4* w4 = (const float4*)(W + (size_t)k * 512 + h * 256);
        const float4* a4 = (const float4*)(a + h * 256);
        float4 w = w4[lane], av = a4[lane];
        sum = w.x*av.x + w.y*av.y + w.z*av.z + w.w*av.w;
    } else {                             // layer 2: 8 j x 512 k, C=64
        int id2 = id - 2048;
        int j = id2 >> 9, k = id2 & 511;
        int r = j >> 2, jj = j & 3, h = jj & 1;
        const float* W = r ? W2_1 : W2_0;                 // [512 x 128]
        const float* a = (jj < 2) ? (r ? as2_1 : as2_0) : (r ? ad2_1 : ad2_0);
        if (lane < 16){
            const float4* w4 = (const float4*)(W + (size_t)k * 128 + h * 64);
            const float4* a4 = (const float4*)(a + h * 64);
            float4 w = w4[lane], av = a4[lane];
            sum = w.x*av.x + w.y*av.y + w.z*av.z + w.w*av.w;
        }
    }
    #pragma unroll
    for (int o = 32; o > 0; o >>= 1) sum += __shfl_down(sum, o, 64);
    if (lane == 0){ if (id < 2048) v1[id] = sum; else v2[id - 2048] = sum; }
}

// ---------------- logits: L[n][8] = X[n,:] @ v[j,:] ----------------
template<int KD>
__global__ __launch_bounds__(256)
void logits_kernel(const float* __restrict__ X, const float* __restrict__ vj,
                   float* __restrict__ L){
    constexpr int F4 = KD / 256;         // float4 loads per lane
    int n = blockIdx.x * 4 + (threadIdx.x >> 6);
    int lane = threadIdx.x & 63;
    float4 xv[F4];
    #pragma unroll
    for (int u = 0; u < F4; u++)
        xv[u] = ((const float4*)(X + (size_t)n * KD))[lane + u * 64];
    float p[8];
    #pragma unroll
    for (int j = 0; j < 8; j++){
        float s = 0.f;
        #pragma unroll
        for (int u = 0; u < F4; u++){
            float4 vv = ((const float4*)(vj + (size_t)j * KD))[lane + u * 64];
            s += xv[u].x*vv.x + xv[u].y*vv.y + xv[u].z*vv.z + xv[u].w*vv.w;
        }
        p[j] = s;
    }
    #pragma unroll
    for (int o = 32; o > 0; o >>= 1)
        #pragma unroll
        for (int j = 0; j < 8; j++) p[j] += __shfl_down(p[j], o, 64);
    if (lane == 0){
        float4 a = {p[0], p[1], p[2], p[3]}, b = {p[4], p[5], p[6], p[7]};
        ((float4*)(L + (size_t)n * 8))[0] = a;
        ((float4*)(L + (size_t)n * 8))[1] = b;
    }
}

// ---------------- fp32 GEMM, 32x32 tile, TM=TN=2, 256 thr, optional split-K ----------------
// grid: (Nn/32, M/32, 2*SPLIT); z&1 = relation, z>>1 = K-split index
template<bool ATOMIC>
__global__ __launch_bounds__(256)
void gemm32(const float* __restrict__ A, const float* __restrict__ B0,
            const float* __restrict__ B1, float* __restrict__ C0,
            float* __restrict__ C1, int Nn, int K, int kchunk){
    int r = blockIdx.z & 1;
    int s = blockIdx.z >> 1;
    const float* __restrict__ B = r ? B1 : B0;
    float* __restrict__ C = r ? C1 : C0;
    int m0 = blockIdx.y * 32, n0 = blockIdx.x * 32;
    __shared__ float As[32][36];   // k-major, pad 4 keeps b128/b64 alignment
    __shared__ float Bs[32][36];
    int tid = threadIdx.x;
    int lm = tid >> 3, l4 = tid & 7;         // staging: row, float4-col
    int tx = tid & 15, ty = tid >> 4;        // compute: 16x16 thread grid
    float acc00 = 0.f, acc01 = 0.f, acc10 = 0.f, acc11 = 0.f;
    int k_beg = s * kchunk;
    const float* Arow = A + (size_t)(m0 + lm) * K + k_beg + l4 * 4;
    const float* Brow = B + (size_t)(k_beg + lm) * Nn + n0 + l4 * 4;
    for (int kt = 0; kt < kchunk; kt += 32){
        float4 a4 = *(const float4*)Arow;
        float4 b4 = *(const float4*)Brow;
        Arow += 32; Brow += (size_t)32 * Nn;
        As[l4*4+0][lm] = a4.x; As[l4*4+1][lm] = a4.y;
        As[l4*4+2][lm] = a4.z; As[l4*4+3][lm] = a4.w;
        *(float4*)&Bs[lm][l4*4] = b4;
        __syncthreads();
        #pragma unroll
        for (int kk = 0; kk < 32; kk++){
            float2 av = *(const float2*)&As[kk][ty*2];
            float2 bv = *(const float2*)&Bs[kk][tx*2];
            acc00 += av.x*bv.x; acc01 += av.x*bv.y;
            acc10 += av.y*bv.x; acc11 += av.y*bv.y;
        }
        __syncthreads();
    }
    size_t c0 = (size_t)(m0 + ty*2) * Nn + n0 + tx*2;
    if (ATOMIC){
        atomicAdd(&C[c0], acc00);      atomicAdd(&C[c0+1], acc01);
        atomicAdd(&C[c0+Nn], acc10);   atomicAdd(&C[c0+Nn+1], acc11);
    } else {
        float2 r0 = {acc00, acc01}, r1 = {acc10, acc11};
        *(float2*)&C[c0] = r0;
        *(float2*)&C[c0 + Nn] = r1;
    }
}

// ---------------- GAT aggregation, both relations fused; optional q-epilogue ----------------
template<int HC, int C, int BLOCK, int TILE, bool QEPI>
__global__ __launch_bounds__(BLOCK)
void gat_agg(const float* __restrict__ xp0, const float* __restrict__ xp1,
             const float* __restrict__ L,
             const int* __restrict__ csr0, const int* __restrict__ csr1,
             const int* __restrict__ rowp0, const int* __restrict__ rowp1,
             const float* __restrict__ b0, const float* __restrict__ b1,
             const float* __restrict__ wl, float* __restrict__ outp){
    constexpr int OPT = HC / BLOCK;
    constexpr int NW = BLOCK / 64;
    int v = blockIdx.x, tid = threadIdx.x;
    __shared__ float wa0[TILE], wa1[TILE];
    __shared__ int   ssrc[TILE];
    __shared__ float rr0[NW], rr1[NW], invs[2];
    float acc[OPT] = {};
    #pragma unroll
    for (int r = 0; r < 2; r++){
        const float* xp  = r ? xp1  : xp0;
        const int* csr   = r ? csr1 : csr0;
        const int* rowp  = r ? rowp1 : rowp0;
        int beg = rowp[v], end = rowp[v+1];
        float ad0 = L[v*8 + r*4 + 2], ad1 = L[v*8 + r*4 + 3];
        // pass 1: softmax denominators (no max-sub: logits O(+-10), segments non-empty)
        float s0 = 0.f, s1 = 0.f;
        for (int e = beg + tid; e < end; e += BLOCK){
            int src = csr[e];
            s0 += __expf(lrelu(L[src*8 + r*4 + 0] + ad0));
            s1 += __expf(lrelu(L[src*8 + r*4 + 1] + ad1));
        }
        #pragma unroll
        for (int o = 32; o > 0; o >>= 1){
            s0 += __shfl_down(s0, o, 64);
            s1 += __shfl_down(s1, o, 64);
        }
        if ((tid & 63) == 0){ rr0[tid>>6] = s0; rr1[tid>>6] = s1; }
        __syncthreads();
        if (tid == 0){
            float S0 = 0.f, S1 = 0.f;
            #pragma unroll
            for (int i = 0; i < NW; i++){ S0 += rr0[i]; S1 += rr1[i]; }
            invs[0] = 1.f / (S0 + 1e-16f);
            invs[1] = 1.f / (S1 + 1e-16f);
        }
        __syncthreads();
        float inv0 = invs[0], inv1 = invs[1];
        // pass 2: chunked weighted gather
        for (int cb = beg; cb < end; cb += TILE){
            int n = min(TILE, end - cb);
            __syncthreads();
            for (int i = tid; i < n; i += BLOCK){
                int src = csr[cb + i];
                ssrc[i] = src * HC;
                wa0[i] = __expf(lrelu(L[src*8 + r*4 + 0] + ad0)) * inv0;
                wa1[i] = __expf(lrelu(L[src*8 + r*4 + 1] + ad1)) * inv1;
            }
            __syncthreads();
            #pragma unroll 8
            for (int i = 0; i < n; i++){
                int sb = ssrc[i];
                float a0 = wa0[i], a1 = wa1[i];
                #pragma unroll
                for (int rp = 0; rp < OPT; rp++){
                    int o = tid + rp * BLOCK;
                    acc[rp] += xp[(size_t)sb + o] * ((o < C) ? a0 : a1);
                }
            }
        }
        __syncthreads();
    }
    if (!QEPI){
        #pragma unroll
        for (int rp = 0; rp < OPT; rp++){
            int o = tid + rp * BLOCK;
            float t = acc[rp] + b0[o] + b1[o];
            outp[(size_t)v * HC + o] = t > 0.f ? t : 0.f;   // relu(h1 + bias0 + bias1)
        }
    } else {
        // q[v] = sum_c (h2[v,c] + b0[c] + b1[c]) * wl[c]   (h2 never materialized)
        float p = (acc[0] + b0[tid] + b1[tid]) * wl[tid];
        #pragma unroll
        for (int o = 32; o > 0; o >>= 1) p += __shfl_down(p, o, 64);
        if ((tid & 63) == 0) rr0[tid>>6] = p;
        __syncthreads();
        if (tid == 0){
            float S = 0.f;
            #pragma unroll
            for (int i = 0; i < NW; i++) S += rr0[i];
            outp[v] = S;
        }
    }
}

// ---------------- out[i*1024 + j] = q[i] + q[j] + b_lin ----------------
__global__ __launch_bounds__(256)
void pairs_out(const float* __restrict__ q, const float* __restrict__ blin,
               float* __restrict__ out){
    int i = blockIdx.x;
    float qi = q[i] + blin[0];
    float4 qj = ((const float4*)q)[threadIdx.x];
    float4 o;
    o.x = qi + qj.x; o.y = qi + qj.y; o.z = qi + qj.z; o.w = qi + qj.w;
    ((float4*)out)[(size_t)i * 256 + threadIdx.x] = o;
}

extern "C" void kernel_launch(void* const* d_in, const int* in_sizes, int n_in,
                              void* d_out, int out_size, void* d_ws, size_t ws_size,
                              hipStream_t stream){
    const float* x    = (const float*)d_in[0];
    const int*   ei0  = (const int*)d_in[1];
    const int*   ei1  = (const int*)d_in[2];
    const float* W1[2]  = {(const float*)d_in[3],  (const float*)d_in[7]};
    const float* as1[2] = {(const float*)d_in[4],  (const float*)d_in[8]};
    const float* ad1[2] = {(const float*)d_in[5],  (const float*)d_in[9]};
    const float* b1[2]  = {(const float*)d_in[6],  (const float*)d_in[10]};
    const float* W2[2]  = {(const float*)d_in[11], (const float*)d_in[15]};
    const float* as2[2] = {(const float*)d_in[12], (const float*)d_in[16]};
    const float* ad2[2] = {(const float*)d_in[13], (const float*)d_in[17]};
    const float* b2[2]  = {(const float*)d_in[14], (const float*)d_in[18]};
    const float* wlin = (const float*)d_in[19];
    const float* blin = (const float*)d_in[20];
    float* out = (float*)d_out;

    const int N = 1024;
    const int E = in_sizes[1] / 2;
    const int TOT = E + N;

    // ---- workspace (bump allocator, 256B aligned) ----
    char* p = (char*)d_ws;
    auto alloc = [&](size_t bytes) -> char* {
        char* r = p; p += (bytes + 255) & ~(size_t)255; return r;
    };
    float* xp1[2] = {(float*)alloc((size_t)N*512*4), (float*)alloc((size_t)N*512*4)};
    float* h1     = (float*)alloc((size_t)N*512*4);
    float* xp2base = (float*)alloc((size_t)2*N*128*4);
    float* xp2[2] = {xp2base, xp2base + (size_t)N*128};
    float* L1 = (float*)alloc((size_t)N*8*4);
    float* L2 = (float*)alloc((size_t)N*8*4);
    float* v1 = (float*)alloc(8*256*4);
    float* v2 = (float*)alloc(8*512*4);
    int* cnt     = (int*)alloc((size_t)2*N*4);
    int* rowp[2] = {(int*)alloc((N+1)*4), (int*)alloc((N+1)*4)};
    int* fill[2] = {(int*)alloc(N*4), (int*)alloc(N*4)};
    int* csr[2]  = {(int*)alloc((size_t)TOT*4), (int*)alloc((size_t)TOT*4)};
    float* q     = (float*)alloc(N*4);

    hipMemsetAsync(cnt, 0, (size_t)2*N*4, stream);
    hipMemsetAsync(xp2base, 0, (size_t)2*N*128*4, stream);   // split-K accumulators

    int eb = (TOT + 255) / 256;
    hist_kernel<<<dim3(eb, 2), 256, 0, stream>>>(ei0, ei1, E, N, cnt);
    scan_kernel<<<2, 1024, 0, stream>>>(cnt, rowp[0], rowp[1], fill[0], fill[1]);
    scatter_kernel<<<dim3(eb, 2), 256, 0, stream>>>(ei0, ei1, E, N,
                                                    fill[0], fill[1], csr[0], csr[1]);

    prep_v<<<6144, 64, 0, stream>>>(W1[0], as1[0], ad1[0], W1[1], as1[1], ad1[1],
                                    W2[0], as2[0], ad2[0], W2[1], as2[1], ad2[1],
                                    v1, v2);

    // layer 1: xp1_r = x @ W1_r  [1024,256]@[256,512]; grid 1024 blocks
    gemm32<false><<<dim3(512/32, 1024/32, 2), 256, 0, stream>>>(
        x, W1[0], W1[1], xp1[0], xp1[1], 512, 256, 256);
    logits_kernel<256><<<N/4, 256, 0, stream>>>(x, v1, L1);
    gat_agg<512,256,256,512,false><<<N, 256, 0, stream>>>(
        xp1[0], xp1[1], L1, csr[0], csr[1], rowp[0], rowp[1],
        b1[0], b1[1], nullptr, h1);

    // layer 2: xp2_r = h1 @ W2_r  [1024,512]@[512,128]; split-K=4 -> 1024 blocks
    gemm32<true><<<dim3(128/32, 1024/32, 8), 256, 0, stream>>>(
        h1, W2[0], W2[1], xp2[0], xp2[1], 128, 512, 128);
    logits_kernel<512><<<N/4, 256, 0, stream>>>(h1, v2, L2);
    gat_agg<128,64,128,512,true><<<N, 128, 0, stream>>>(
        xp2[0], xp2[1], L2, csr[0], csr[1], rowp[0], rowp[1],
        b2[0], b2[1], wlin, q);

    pairs_out<<<N, 256, 0, stream>>>(q, blin, out);
}

// Round 3
// 209.531 us; speedup vs baseline: 1.4702x; 1.0086x over previous
//
#include <hip/hip_runtime.h>
#include <hip/hip_bf16.h>

// HeteroGNN: 2-relation 2-layer GAT + pairwise linear head.
// out[i*N+j] = q[i] + q[j] + b_lin with q = (h2 + biases) @ w_lin  (head collapses).
// Logits via associativity: al = (x@W)·a = x @ (W·a)  -> tiny v-matrix.
// xp (projected features) stored bf16 for the gather (traffic/instr halved);
// all accumulation + logits + h1 stay fp32.

#define NEG_SLOPE 0.2f
static __device__ __forceinline__ float lrelu(float x){ return x > 0.f ? x : NEG_SLOPE * x; }

// ---------------- CSR build (by dst), both relations per launch ----------------
__global__ void hist_kernel(const int* __restrict__ ei0, const int* __restrict__ ei1,
                            int E, int Nn, int* __restrict__ cnt){
    const int* ei = blockIdx.y ? ei1 : ei0;
    int* c = cnt + blockIdx.y * Nn;
    int e = blockIdx.x * blockDim.x + threadIdx.x;
    if (e < E + Nn){
        int dst = (e < E) ? ei[E + e] : (e - E);   // self-loops appended
        atomicAdd(&c[dst], 1);
    }
}

__global__ __launch_bounds__(1024)
void scan_kernel(const int* __restrict__ cnt,
                 int* __restrict__ rowp0, int* __restrict__ rowp1,
                 int* __restrict__ fill0, int* __restrict__ fill1){
    int r = blockIdx.x;
    const int* cn = cnt + r * 1024;
    int* rowp = r ? rowp1 : rowp0;
    int* fill = r ? fill1 : fill0;
    __shared__ int s[1024];
    int tid = threadIdx.x;
    int c = cn[tid];
    s[tid] = c; __syncthreads();
    for (int off = 1; off < 1024; off <<= 1){
        int v = (tid >= off) ? s[tid - off] : 0;
        __syncthreads();
        s[tid] += v;
        __syncthreads();
    }
    rowp[tid + 1] = s[tid];
    if (tid == 0) rowp[0] = 0;
    fill[tid] = s[tid] - c;
}

__global__ void scatter_kernel(const int* __restrict__ ei0, const int* __restrict__ ei1,
                               int E, int Nn,
                               int* __restrict__ fill0, int* __restrict__ fill1,
                               int* __restrict__ csr0, int* __restrict__ csr1){
    const int* ei = blockIdx.y ? ei1 : ei0;
    int* fill = blockIdx.y ? fill1 : fill0;
    int* csr  = blockIdx.y ? csr1  : csr0;
    int e = blockIdx.x * blockDim.x + threadIdx.x;
    if (e < E + Nn){
        int src, dst;
        if (e < E){ src = ei[e]; dst = ei[E + e]; } else { src = dst = e - E; }
        csr[atomicAdd(&fill[dst], 1)] = src;
    }
}

// ---------------- v = W·a  precompute (logit weight vectors), j-major ----------------
// v1: [8][256], v2: [8][512]; j = r*4 + {0:src h0, 1:src h1, 2:dst h0, 3:dst h1}
__global__ __launch_bounds__(64)
void prep_v(const float* __restrict__ W1_0, const float* __restrict__ as1_0,
            const float* __restrict__ ad1_0,
            const float* __restrict__ W1_1, const float* __restrict__ as1_1,
            const float* __restrict__ ad1_1,
            const float* __restrict__ W2_0, const float* __restrict__ as2_0,
            const float* __restrict__ ad2_0,
            const float* __restrict__ W2_1, const float* __restrict__ as2_1,
            const float* __restrict__ ad2_1,
            float* __restrict__ v1, float* __restrict__ v2){
    int id = blockIdx.x, lane = threadIdx.x;
    float sum = 0.f;
    if (id < 2048){                      // layer 1: 8 j x 256 k, C=256
        int j = id >> 8, k = id & 255;
        int r = j >> 2, jj = j & 3, h = jj & 1;
        const float* W = r ? W1_1 : W1_0;                 // [256 x 512]
        const float* a = (jj < 2) ? (r ? as1_1 : as1_0) : (r ? ad1_1 : ad1_0);
        const float4* w4 = (const float4*)(W + (size_t)k * 512 + h * 256);
        const float4* a4 = (const float4*)(a + h * 256);
        float4 w = w4[lane], av = a4[lane];
        sum = w.x*av.x + w.y*av.y + w.z*av.z + w.w*av.w;
    } else {                             // layer 2: 8 j x 512 k, C=64
        int id2 = id - 2048;
        int j = id2 >> 9, k = id2 & 511;
        int r = j >> 2, jj = j & 3, h = jj & 1;
        const float* W = r ? W2_1 : W2_0;                 // [512 x 128]
        const float* a = (jj < 2) ? (r ? as2_1 : as2_0) : (r ? ad2_1 : ad2_0);
        if (lane < 16){
            const float4* w4 = (const float4*)(W + (size_t)k * 128 + h * 64);
            const float4* a4 = (const float4*)(a + h * 64);
            float4 w = w4[lane], av = a4[lane];
            sum = w.x*av.x + w.y*av.y + w.z*av.z + w.w*av.w;
        }
    }
    #pragma unroll
    for (int o = 32; o > 0; o >>= 1) sum += __shfl_down(sum, o, 64);
    if (lane == 0){ if (id < 2048) v1[id] = sum; else v2[id - 2048] = sum; }
}

// ---------------- logits: L[n][8] = X[n,:] @ v[j,:]  (fp32, X = x or h1) ----------------
template<int KD>
__global__ __launch_bounds__(256)
void logits_kernel(const float* __restrict__ X, const float* __restrict__ vj,
                   float* __restrict__ L){
    constexpr int F4 = KD / 256;         // float4 loads per lane
    int n = blockIdx.x * 4 + (threadIdx.x >> 6);
    int lane = threadIdx.x & 63;
    float4 xv[F4];
    #pragma unroll
    for (int u = 0; u < F4; u++)
        xv[u] = ((const float4*)(X + (size_t)n * KD))[lane + u * 64];
    float p[8];
    #pragma unroll
    for (int j = 0; j < 8; j++){
        float s = 0.f;
        #pragma unroll
        for (int u = 0; u < F4; u++){
            float4 vv = ((const float4*)(vj + (size_t)j * KD))[lane + u * 64];
            s += xv[u].x*vv.x + xv[u].y*vv.y + xv[u].z*vv.z + xv[u].w*vv.w;
        }
        p[j] = s;
    }
    #pragma unroll
    for (int o = 32; o > 0; o >>= 1)
        #pragma unroll
        for (int j = 0; j < 8; j++) p[j] += __shfl_down(p[j], o, 64);
    if (lane == 0){
        float4 a = {p[0], p[1], p[2], p[3]}, b = {p[4], p[5], p[6], p[7]};
        ((float4*)(L + (size_t)n * 8))[0] = a;
        ((float4*)(L + (size_t)n * 8))[1] = b;
    }
}

// ---------------- fp32 GEMM -> bf16 output, both relations via blockIdx.z ----------------
// BK=32, BN=32, TN=2 fixed by staging math; NT = (BM/TM)*(BN/TN) threads.
template<int BM, int TM>
__global__ __launch_bounds__((BM/TM)*16)
void gemm_bf(const float* __restrict__ A, const float* __restrict__ B0,
             const float* __restrict__ B1, __hip_bfloat162* __restrict__ C0,
             __hip_bfloat162* __restrict__ C1, int Nn, int K){
    constexpr int BK = 32, BN = 32, TN = 2;
    constexpr int NT = (BM/TM) * (BN/TN);
    constexpr int AF4 = BM * BK / 4 / NT;
    constexpr int BF4 = BK * BN / 4 / NT;
    const float* __restrict__ B = blockIdx.z ? B1 : B0;
    __hip_bfloat162* __restrict__ C = blockIdx.z ? C1 : C0;
    int m0 = blockIdx.y * BM, n0 = blockIdx.x * BN;
    __shared__ float As[BK][BM + 4];   // k-major (transposed store)
    __shared__ float Bs[BK][BN + 8];   // +8 keeps rows 16B-aligned for float4 store
    int tid = threadIdx.x;
    int tx = tid & 15, ty = tid >> 4;
    float acc[TM][TN] = {};
    for (int k0 = 0; k0 < K; k0 += BK){
        #pragma unroll
        for (int u = 0; u < AF4; u++){
            int f = u * NT + tid;
            int am = f >> 3, ac4 = f & 7;            // BK/4 = 8
            float4 a4 = *(const float4*)(A + (size_t)(m0 + am) * K + k0 + ac4 * 4);
            As[ac4*4+0][am] = a4.x; As[ac4*4+1][am] = a4.y;
            As[ac4*4+2][am] = a4.z; As[ac4*4+3][am] = a4.w;
        }
        #pragma unroll
        for (int u = 0; u < BF4; u++){
            int f = u * NT + tid;
            int bk = f >> 3, bc4 = f & 7;            // BN/4 = 8
            *(float4*)&Bs[bk][bc4*4] =
                *(const float4*)(B + (size_t)(k0 + bk) * Nn + n0 + bc4 * 4);
        }
        __syncthreads();
        #pragma unroll
        for (int kk = 0; kk < BK; kk++){
            float ar[TM], br[TN];
            #pragma unroll
            for (int i = 0; i < TM; i++) ar[i] = As[kk][ty*TM + i];
            #pragma unroll
            for (int j = 0; j < TN; j++) br[j] = Bs[kk][tx*TN + j];
            #pragma unroll
            for (int i = 0; i < TM; i++)
                #pragma unroll
                for (int j = 0; j < TN; j++)
                    acc[i][j] += ar[i] * br[j];
        }
        __syncthreads();
    }
    #pragma unroll
    for (int i = 0; i < TM; i++){
        int row = m0 + ty*TM + i, col = n0 + tx*TN;
        __hip_bfloat162 t;
        t.x = __float2bfloat16(acc[i][0]);
        t.y = __float2bfloat16(acc[i][1]);
        C[((size_t)row * Nn + col) >> 1] = t;
    }
}

// ---------------- GAT aggregation over bf16 xp, both relations fused ----------------
// PAIRS = HC/2 bf16x2 lanes; BLOCK == PAIRS (1 dword load per thread per edge).
template<int HC, int C, int BLOCK, int TILE, bool QEPI>
__global__ __launch_bounds__(BLOCK)
void gat_agg(const __hip_bfloat162* __restrict__ xp0,
             const __hip_bfloat162* __restrict__ xp1,
             const float* __restrict__ L,
             const int* __restrict__ csr0, const int* __restrict__ csr1,
             const int* __restrict__ rowp0, const int* __restrict__ rowp1,
             const float* __restrict__ b0, const float* __restrict__ b1,
             const float* __restrict__ wl, float* __restrict__ outp){
    constexpr int PAIRS = HC / 2;
    static_assert(PAIRS == BLOCK, "one dword per thread per edge");
    constexpr int NW = BLOCK / 64;
    int v = blockIdx.x, tid = threadIdx.x;
    bool head0 = tid < (C >> 1);
    __shared__ float wa0[TILE], wa1[TILE];
    __shared__ int   ssrc[TILE];
    __shared__ float rr0[NW], rr1[NW], invs[2];
    float acc0 = 0.f, acc1 = 0.f;
    #pragma unroll
    for (int r = 0; r < 2; r++){
        const __hip_bfloat162* xp = r ? xp1 : xp0;
        const int* csr  = r ? csr1 : csr0;
        const int* rowp = r ? rowp1 : rowp0;
        int beg = rowp[v], end = rowp[v+1];
        float ad0 = L[v*8 + r*4 + 2], ad1 = L[v*8 + r*4 + 3];
        // pass 1: softmax denominators (no max-sub: logits O(+-10), segments non-empty)
        float s0 = 0.f, s1 = 0.f;
        for (int e = beg + tid; e < end; e += BLOCK){
            int src = csr[e];
            s0 += __expf(lrelu(L[src*8 + r*4 + 0] + ad0));
            s1 += __expf(lrelu(L[src*8 + r*4 + 1] + ad1));
        }
        #pragma unroll
        for (int o = 32; o > 0; o >>= 1){
            s0 += __shfl_down(s0, o, 64);
            s1 += __shfl_down(s1, o, 64);
        }
        if ((tid & 63) == 0){ rr0[tid>>6] = s0; rr1[tid>>6] = s1; }
        __syncthreads();
        if (tid == 0){
            float S0 = 0.f, S1 = 0.f;
            #pragma unroll
            for (int i = 0; i < NW; i++){ S0 += rr0[i]; S1 += rr1[i]; }
            invs[0] = 1.f / (S0 + 1e-16f);
            invs[1] = 1.f / (S1 + 1e-16f);
        }
        __syncthreads();
        float inv0 = invs[0], inv1 = invs[1];
        // pass 2: chunked weighted gather (bf16 features, fp32 accumulate)
        for (int cb = beg; cb < end; cb += TILE){
            int n = min(TILE, end - cb);
            __syncthreads();
            for (int i = tid; i < n; i += BLOCK){
                int src = csr[cb + i];
                ssrc[i] = src * PAIRS;
                wa0[i] = __expf(lrelu(L[src*8 + r*4 + 0] + ad0)) * inv0;
                wa1[i] = __expf(lrelu(L[src*8 + r*4 + 1] + ad1)) * inv1;
            }
            __syncthreads();
            #pragma unroll 16
            for (int i = 0; i < n; i++){
                __hip_bfloat162 w = xp[ssrc[i] + tid];
                float a = head0 ? wa0[i] : wa1[i];
                acc0 += __bfloat162float(w.x) * a;
                acc1 += __bfloat162float(w.y) * a;
            }
        }
        __syncthreads();
    }
    int c0 = 2*tid, c1 = 2*tid + 1;
    if (!QEPI){
        float t0 = acc0 + b0[c0] + b1[c0];
        float t1 = acc1 + b0[c1] + b1[c1];
        float2 o = { t0 > 0.f ? t0 : 0.f, t1 > 0.f ? t1 : 0.f };
        *(float2*)&outp[(size_t)v * HC + c0] = o;      // relu(h1 + bias0 + bias1)
    } else {
        // q[v] = sum_c (h2[v,c] + b0[c] + b1[c]) * wl[c]   (h2 never materialized)
        float p = (acc0 + b0[c0] + b1[c0]) * wl[c0]
                + (acc1 + b0[c1] + b1[c1]) * wl[c1];
        #pragma unroll
        for (int o = 32; o > 0; o >>= 1) p += __shfl_down(p, o, 64);
        if ((tid & 63) == 0) rr0[tid>>6] = p;
        __syncthreads();
        if (tid == 0){
            float S = 0.f;
            #pragma unroll
            for (int i = 0; i < NW; i++) S += rr0[i];
            outp[v] = S;
        }
    }
}

// ---------------- out[i*1024 + j] = q[i] + q[j] + b_lin ----------------
__global__ __launch_bounds__(256)
void pairs_out(const float* __restrict__ q, const float* __restrict__ blin,
               float* __restrict__ out){
    int i = blockIdx.x;
    float qi = q[i] + blin[0];
    float4 qj = ((const float4*)q)[threadIdx.x];
    float4 o;
    o.x = qi + qj.x; o.y = qi + qj.y; o.z = qi + qj.z; o.w = qi + qj.w;
    ((float4*)out)[(size_t)i * 256 + threadIdx.x] = o;
}

extern "C" void kernel_launch(void* const* d_in, const int* in_sizes, int n_in,
                              void* d_out, int out_size, void* d_ws, size_t ws_size,
                              hipStream_t stream){
    const float* x    = (const float*)d_in[0];
    const int*   ei0  = (const int*)d_in[1];
    const int*   ei1  = (const int*)d_in[2];
    const float* W1[2]  = {(const float*)d_in[3],  (const float*)d_in[7]};
    const float* as1[2] = {(const float*)d_in[4],  (const float*)d_in[8]};
    const float* ad1[2] = {(const float*)d_in[5],  (const float*)d_in[9]};
    const float* b1[2]  = {(const float*)d_in[6],  (const float*)d_in[10]};
    const float* W2[2]  = {(const float*)d_in[11], (const float*)d_in[15]};
    const float* as2[2] = {(const float*)d_in[12], (const float*)d_in[16]};
    const float* ad2[2] = {(const float*)d_in[13], (const float*)d_in[17]};
    const float* b2[2]  = {(const float*)d_in[14], (const float*)d_in[18]};
    const float* wlin = (const float*)d_in[19];
    const float* blin = (const float*)d_in[20];
    float* out = (float*)d_out;

    const int N = 1024;
    const int E = in_sizes[1] / 2;
    const int TOT = E + N;

    // ---- workspace (bump allocator, 256B aligned) ----
    char* p = (char*)d_ws;
    auto alloc = [&](size_t bytes) -> char* {
        char* r = p; p += (bytes + 255) & ~(size_t)255; return r;
    };
    __hip_bfloat162* xp1[2] = {(__hip_bfloat162*)alloc((size_t)N*512*2),
                               (__hip_bfloat162*)alloc((size_t)N*512*2)};
    float* h1 = (float*)alloc((size_t)N*512*4);
    __hip_bfloat162* xp2[2] = {(__hip_bfloat162*)alloc((size_t)N*128*2),
                               (__hip_bfloat162*)alloc((size_t)N*128*2)};
    float* L1 = (float*)alloc((size_t)N*8*4);
    float* L2 = (float*)alloc((size_t)N*8*4);
    float* v1 = (float*)alloc(8*256*4);
    float* v2 = (float*)alloc(8*512*4);
    int* cnt     = (int*)alloc((size_t)2*N*4);
    int* rowp[2] = {(int*)alloc((N+1)*4), (int*)alloc((N+1)*4)};
    int* fill[2] = {(int*)alloc(N*4), (int*)alloc(N*4)};
    int* csr[2]  = {(int*)alloc((size_t)TOT*4), (int*)alloc((size_t)TOT*4)};
    float* q     = (float*)alloc(N*4);

    hipMemsetAsync(cnt, 0, (size_t)2*N*4, stream);

    int eb = (TOT + 255) / 256;
    hist_kernel<<<dim3(eb, 2), 256, 0, stream>>>(ei0, ei1, E, N, cnt);
    scan_kernel<<<2, 1024, 0, stream>>>(cnt, rowp[0], rowp[1], fill[0], fill[1]);
    scatter_kernel<<<dim3(eb, 2), 256, 0, stream>>>(ei0, ei1, E, N,
                                                    fill[0], fill[1], csr[0], csr[1]);

    prep_v<<<6144, 64, 0, stream>>>(W1[0], as1[0], ad1[0], W1[1], as1[1], ad1[1],
                                    W2[0], as2[0], ad2[0], W2[1], as2[1], ad2[1],
                                    v1, v2);

    // layer 1: xp1_r = bf16(x @ W1_r)  [1024,256]@[256,512]; 64x32 tile, 512 blocks
    gemm_bf<64,4><<<dim3(512/32, 1024/64, 2), 256, 0, stream>>>(
        x, W1[0], W1[1], xp1[0], xp1[1], 512, 256);
    logits_kernel<256><<<N/4, 256, 0, stream>>>(x, v1, L1);
    gat_agg<512,256,256,512,false><<<N, 256, 0, stream>>>(
        xp1[0], xp1[1], L1, csr[0], csr[1], rowp[0], rowp[1],
        b1[0], b1[1], nullptr, h1);

    // layer 2: xp2_r = bf16(h1 @ W2_r)  [1024,512]@[512,128]; 16x32 tile, 512 blocks
    gemm_bf<16,2><<<dim3(128/32, 1024/16, 2), 128, 0, stream>>>(
        h1, W2[0], W2[1], xp2[0], xp2[1], 128, 512);
    logits_kernel<512><<<N/4, 256, 0, stream>>>(h1, v2, L2);
    gat_agg<128,64,64,128,true><<<N, 64, 0, stream>>>(
        xp2[0], xp2[1], L2, csr[0], csr[1], rowp[0], rowp[1],
        b2[0], b2[1], wlin, q);

    pairs_out<<<N, 256, 0, stream>>>(q, blin, out);
}